// Round 1
// baseline (1252.300 us; speedup 1.0000x reference)
//
#include <hip/hip_runtime.h>
#include <hip/hip_bf16.h>
#include <stdint.h>

#define VOCAB 32000
#define EMBED 1024
#define HEADS 16
#define SEQ   2048
#define BATCH 2
#define HD    64

typedef __attribute__((ext_vector_type(8))) __bf16 bf16x8;
typedef __attribute__((ext_vector_type(4))) __bf16 bf16x4;
typedef __attribute__((ext_vector_type(4))) float f32x4;
typedef __attribute__((ext_vector_type(8))) unsigned short u16x8;

__device__ __forceinline__ void gload16(const void* g, void* l) {
  __builtin_amdgcn_global_load_lds((const __attribute__((address_space(1))) void*)g,
                                   (__attribute__((address_space(3))) void*)l,
                                   16, 0, 0);
}

// ---------------- embed gather: x[i,:] = emb[idx[i],:], fp32 + bf16 ----------------
__global__ __launch_bounds__(256) void k_embed(const int* __restrict__ idx,
                                               const float* __restrict__ emb,
                                               float* __restrict__ xf,
                                               __bf16* __restrict__ xb) {
  const int row = blockIdx.x;     // 4096 rows
  const int t = threadIdx.x;      // 256 threads * float4 = 1024 floats
  const int src = idx[row];
  float4 v = reinterpret_cast<const float4*>(emb + (size_t)src * EMBED)[t];
  reinterpret_cast<float4*>(xf + (size_t)row * EMBED)[t] = v;
  bf16x4 b;
  b[0] = (__bf16)v.x; b[1] = (__bf16)v.y; b[2] = (__bf16)v.z; b[3] = (__bf16)v.w;
  reinterpret_cast<bf16x4*>(xb + (size_t)row * EMBED)[t] = b;
}

// ---------------- f32 -> bf16 bulk convert (n4 = n/4) ----------------
__global__ __launch_bounds__(256) void k_f2b(const float* __restrict__ in,
                                             __bf16* __restrict__ out, int n4) {
  int i = blockIdx.x * 256 + threadIdx.x;
  if (i >= n4) return;
  float4 v = reinterpret_cast<const float4*>(in)[i];
  bf16x4 b;
  b[0] = (__bf16)v.x; b[1] = (__bf16)v.y; b[2] = (__bf16)v.z; b[3] = (__bf16)v.w;
  reinterpret_cast<bf16x4*>(out)[i] = b;
}

// ---------------- GEMM: C[M,N] = A[M,K] * Bt[N,K]^T (all row-major, bf16 in) -------
// m97 structure: 128x128 tile, BK=32, 256 threads (4 waves, 2x2 of 64x64),
// global_load_lds width 16. MODE 0: fp32 C. MODE 1: bf16 C. MODE 2: bf16(C+resid).
template<int MODE>
__global__ __launch_bounds__(256) void k_gemm(const __bf16* __restrict__ A,
                                              const __bf16* __restrict__ Bt,
                                              int M, int N, int K,
                                              float* __restrict__ Cf,
                                              __bf16* __restrict__ Cb,
                                              const float* __restrict__ resid) {
  __shared__ __bf16 As[128 * 32];
  __shared__ __bf16 Bs[128 * 32];
  const int tid = threadIdx.x;
  const int wid = tid >> 6, lane = tid & 63;
  const int m0 = blockIdx.x * 128, n0 = blockIdx.y * 128;
  const int wr = wid >> 1, wc = wid & 1;

  // staging: thread t loads 16B chunk t of the 8KB tile (2 sweeps of 4KB)
  const int arow = tid >> 2, acol = (tid & 3) * 8;
  const __bf16* ga0 = A + (size_t)(m0 + arow) * K + acol;
  const __bf16* ga1 = A + (size_t)(m0 + arow + 64) * K + acol;
  const __bf16* gb0 = Bt + (size_t)(n0 + arow) * K + acol;
  const __bf16* gb1 = Bt + (size_t)(n0 + arow + 64) * K + acol;
  __bf16* lA0 = As + wid * 512;           // wave-uniform LDS bases
  __bf16* lA1 = As + wid * 512 + 2048;
  __bf16* lB0 = Bs + wid * 512;
  __bf16* lB1 = Bs + wid * 512 + 2048;

  f32x4 acc[4][4] = {};
  const int lr = lane & 15;
  const int kchunk = (lane >> 4) * 8;

  for (int k0 = 0; k0 < K; k0 += 32) {
    gload16(ga0 + k0, lA0);
    gload16(ga1 + k0, lA1);
    gload16(gb0 + k0, lB0);
    gload16(gb1 + k0, lB1);
    __syncthreads();   // drains vmcnt -> LDS tiles valid
    bf16x8 a[4], b[4];
#pragma unroll
    for (int i = 0; i < 4; ++i) {
      a[i] = *reinterpret_cast<const bf16x8*>(&As[(wr * 64 + i * 16 + lr) * 32 + kchunk]);
      b[i] = *reinterpret_cast<const bf16x8*>(&Bs[(wc * 64 + i * 16 + lr) * 32 + kchunk]);
    }
#pragma unroll
    for (int i = 0; i < 4; ++i)
#pragma unroll
      for (int j = 0; j < 4; ++j)
        acc[i][j] = __builtin_amdgcn_mfma_f32_16x16x32_bf16(a[i], b[j], acc[i][j], 0, 0, 0);
    __syncthreads();
  }

  // C/D layout: row=(lane>>4)*4+r, col=lane&15 (m89/m91-verified)
  const int r0 = (lane >> 4) * 4;
#pragma unroll
  for (int i = 0; i < 4; ++i)
#pragma unroll
    for (int j = 0; j < 4; ++j)
#pragma unroll
      for (int r = 0; r < 4; ++r) {
        const int row = m0 + wr * 64 + i * 16 + r0 + r;
        const int col = n0 + wc * 64 + j * 16 + lr;
        const size_t o = (size_t)row * N + col;
        if constexpr (MODE == 0)      Cf[o] = acc[i][j][r];
        else if constexpr (MODE == 1) Cb[o] = (__bf16)acc[i][j][r];
        else                          Cb[o] = (__bf16)(acc[i][j][r] + resid[o]);
      }
}

// ---------------- causal flash attention ----------------
// grid (T/64, B*H), 256 threads = 4 waves; wave w owns q rows [q0+16w, q0+16w+16)
// K tile [64][64] via global_load_lds with source-pre-swizzled 16B chunks
// (byte ^= (row&7)<<4 involution) so ds_read_b128 is ~conflict-free.
// V staged transposed Vt[d][kv] via reg transpose + packed b32 swizzled writes.
__global__ __launch_bounds__(256) void k_attn(const __bf16* __restrict__ qb,
                                              const __bf16* __restrict__ kb,
                                              const __bf16* __restrict__ vb,
                                              __bf16* __restrict__ ctx) {
  __shared__ __bf16 Ks[64 * 64];
  __shared__ __bf16 Vt[64 * 64];
  __shared__ __bf16 Ps[4][16 * 64];   // per-wave P buffer

  const int tid = threadIdx.x, wid = tid >> 6, lane = tid & 63;
  const int bq = blockIdx.x;
  const int bh = blockIdx.y;
  const int b = bh >> 4, h = bh & 15;
  const int q0 = bq * 64;

  // Q fragments held in regs: A-operand rows = lane&15, k = h2*32 + (lane>>4)*8 + j
  const size_t qoff = (size_t)(b * SEQ + q0 + wid * 16 + (lane & 15)) * EMBED + h * HD;
  const bf16x8 qf0 = *reinterpret_cast<const bf16x8*>(qb + qoff + (lane >> 4) * 8);
  const bf16x8 qf1 = *reinterpret_cast<const bf16x8*>(qb + qoff + 32 + (lane >> 4) * 8);

  // K staging: LDS slot (row, c) gets global chunk c ^ (row&7)
  const int krow = tid >> 3;                       // 0..31 (sweep 2: +32, same row&7)
  const int kcs = (tid & 7) ^ (krow & 7);
  const __bf16* kg = kb + (size_t)(b * SEQ + krow) * EMBED + h * HD + kcs * 8;
  __bf16* lK0 = Ks + wid * 512;
  __bf16* lK1 = Ks + wid * 512 + 2048;

  // V staging: thread loads rows vkv,vkv+1 chunk vd0, writes packed pairs to Vt
  const int vkv = (tid & 31) * 2;
  const int vd0 = (tid >> 5) * 8;
  const __bf16* vg = vb + (size_t)(b * SEQ + vkv) * EMBED + h * HD + vd0;

  f32x4 o[4] = {};
  float mrow[4] = {-1e30f, -1e30f, -1e30f, -1e30f};
  float lsum[4] = {0.f, 0.f, 0.f, 0.f};

  char* const pbase = (char*)&Ps[wid][0];
  const char* const ksb = (const char*)Ks;
  const char* const vtb = (const char*)Vt;

  const int ntiles = bq + 1;                       // causal: only kv tiles <= q tile
  for (int t = 0; t < ntiles; ++t) {
    const size_t kvo = (size_t)t * 64 * EMBED;
    gload16(kg + kvo, lK0);
    gload16(kg + kvo + (size_t)32 * EMBED, lK1);
    u16x8 v0 = *reinterpret_cast<const u16x8*>(vg + kvo);
    u16x8 v1 = *reinterpret_cast<const u16x8*>(vg + kvo + EMBED);
#pragma unroll
    for (int j = 0; j < 8; ++j) {
      uint32_t val = (uint32_t)v0[j] | ((uint32_t)v1[j] << 16);
      *(uint32_t*)((char*)Vt + (vd0 + j) * 128 + ((vkv * 2) ^ (j << 4))) = val;
    }
    __syncthreads();

    // S = Q K^T  (16 x 64 per wave)
    f32x4 s[4];
#pragma unroll
    for (int nb = 0; nb < 4; ++nb) {
      const int n = nb * 16 + (lane & 15);
      const int c0 = (lane >> 4) ^ (n & 7);
      const int c1 = ((lane >> 4) + 4) ^ (n & 7);
      bf16x8 kf0 = *reinterpret_cast<const bf16x8*>(ksb + n * 128 + c0 * 16);
      bf16x8 kf1 = *reinterpret_cast<const bf16x8*>(ksb + n * 128 + c1 * 16);
      f32x4 z = {};
      z = __builtin_amdgcn_mfma_f32_16x16x32_bf16(qf0, kf0, z, 0, 0, 0);
      z = __builtin_amdgcn_mfma_f32_16x16x32_bf16(qf1, kf1, z, 0, 0, 0);
      s[nb] = z;
    }

    // scale + causal mask (element row = (lane>>4)*4+r, col = nb*16 + (lane&15))
    const int kvb = t * 64;
    const int qrow0 = q0 + wid * 16 + (lane >> 4) * 4;
#pragma unroll
    for (int nb = 0; nb < 4; ++nb) {
      const int kcol = kvb + nb * 16 + (lane & 15);
#pragma unroll
      for (int r = 0; r < 4; ++r) {
        float x = s[nb][r] * 0.125f;
        s[nb][r] = (kcol <= qrow0 + r) ? x : -1e30f;
      }
    }

    // online softmax: reduce across the 16 lanes (lane&15) holding a row's cols
    float pmax[4], alpha[4], rsum[4];
#pragma unroll
    for (int r = 0; r < 4; ++r)
      pmax[r] = fmaxf(fmaxf(s[0][r], s[1][r]), fmaxf(s[2][r], s[3][r]));
#pragma unroll
    for (int off = 1; off < 16; off <<= 1)
#pragma unroll
      for (int r = 0; r < 4; ++r)
        pmax[r] = fmaxf(pmax[r], __shfl_xor(pmax[r], off, 64));
#pragma unroll
    for (int r = 0; r < 4; ++r) {
      float mn = fmaxf(mrow[r], pmax[r]);
      alpha[r] = __expf(mrow[r] - mn);
      mrow[r] = mn;
      rsum[r] = 0.f;
    }
#pragma unroll
    for (int nb = 0; nb < 4; ++nb)
#pragma unroll
      for (int r = 0; r < 4; ++r) {
        float p = __expf(s[nb][r] - mrow[r]);
        s[nb][r] = p;
        rsum[r] += p;
      }
#pragma unroll
    for (int off = 1; off < 16; off <<= 1)
#pragma unroll
      for (int r = 0; r < 4; ++r)
        rsum[r] += __shfl_xor(rsum[r], off, 64);
#pragma unroll
    for (int r = 0; r < 4; ++r)
      lsum[r] = lsum[r] * alpha[r] + rsum[r];
#pragma unroll
    for (int nb = 0; nb < 4; ++nb)
#pragma unroll
      for (int r = 0; r < 4; ++r)
        o[nb][r] *= alpha[r];

    // P -> wave-private LDS (swizzled), then read back as A-fragments
#pragma unroll
    for (int nb = 0; nb < 4; ++nb)
#pragma unroll
      for (int r = 0; r < 4; ++r) {
        const int pr = (lane >> 4) * 4 + r;
        const int pc = nb * 16 + (lane & 15);
        *(__bf16*)(pbase + pr * 128 + ((pc * 2) ^ ((pr & 7) << 4))) = (__bf16)s[nb][r];
      }
    const int ar = lane & 15;
    const int aswz = (ar & 7) << 4;
    bf16x8 pf0 = *reinterpret_cast<const bf16x8*>(pbase + ar * 128 + (((lane >> 4) * 16) ^ aswz));
    bf16x8 pf1 = *reinterpret_cast<const bf16x8*>(pbase + ar * 128 + ((64 + (lane >> 4) * 16) ^ aswz));

    // O += P V
#pragma unroll
    for (int nb = 0; nb < 4; ++nb) {
      const int n = nb * 16 + (lane & 15);
      const int vswz = (n & 7) << 4;
      bf16x8 vf0 = *reinterpret_cast<const bf16x8*>(vtb + n * 128 + (((lane >> 4) * 16) ^ vswz));
      bf16x8 vf1 = *reinterpret_cast<const bf16x8*>(vtb + n * 128 + ((64 + (lane >> 4) * 16) ^ vswz));
      o[nb] = __builtin_amdgcn_mfma_f32_16x16x32_bf16(pf0, vf0, o[nb], 0, 0, 0);
      o[nb] = __builtin_amdgcn_mfma_f32_16x16x32_bf16(pf1, vf1, o[nb], 0, 0, 0);
    }
    __syncthreads();
  }

  // epilogue: O /= l, write ctx bf16 at [b*T+row, h*64+d]
  const int orow = q0 + wid * 16 + (lane >> 4) * 4;
#pragma unroll
  for (int nb = 0; nb < 4; ++nb)
#pragma unroll
    for (int r = 0; r < 4; ++r) {
      const float v = o[nb][r] / lsum[r];
      ctx[(size_t)(b * SEQ + orow + r) * EMBED + h * HD + nb * 16 + (lane & 15)] = (__bf16)v;
    }
}

// ---------------- launch ----------------
extern "C" void kernel_launch(void* const* d_in, const int* in_sizes, int n_in,
                              void* d_out, int out_size, void* d_ws, size_t ws_size,
                              hipStream_t stream) {
  const int*   idx = (const int*)d_in[0];
  const float* emb = (const float*)d_in[1];
  const float* wq  = (const float*)d_in[2];
  const float* wk  = (const float*)d_in[3];
  const float* wv  = (const float*)d_in[4];
  const float* wo  = (const float*)d_in[5];
  const float* wfc = (const float*)d_in[6];
  float* out = (float*)d_out;

  char* ws = (char*)d_ws;
  float*  xf  = (float*)(ws);                  // 16 MB fp32 x (for residual)
  __bf16* xb  = (__bf16*)(ws + 16777216);      // 8 MB
  __bf16* qbf = (__bf16*)(ws + 25165824);      // 8 MB
  __bf16* kbf = (__bf16*)(ws + 33554432);      // 8 MB
  __bf16* vbf = (__bf16*)(ws + 41943040);      // 8 MB
  __bf16* cbf = (__bf16*)(ws + 50331648);      // 8 MB attention ctx
  __bf16* x2b = (__bf16*)(ws + 58720256);      // 8 MB x + attn_out (bf16)
  __bf16* wqb = (__bf16*)(ws + 67108864);      // 2 MB
  __bf16* wkb = (__bf16*)(ws + 69206016);
  __bf16* wvb = (__bf16*)(ws + 71303168);
  __bf16* wob = (__bf16*)(ws + 73400320);
  __bf16* wfb = (__bf16*)(ws + 75497472);      // 65.5 MB  (total ~134.5 MB)

  k_embed<<<dim3(4096), dim3(256), 0, stream>>>(idx, emb, xf, xb);
  k_f2b<<<dim3(1024), dim3(256), 0, stream>>>(wq, wqb, 262144);
  k_f2b<<<dim3(1024), dim3(256), 0, stream>>>(wk, wkb, 262144);
  k_f2b<<<dim3(1024), dim3(256), 0, stream>>>(wv, wvb, 262144);
  k_f2b<<<dim3(1024), dim3(256), 0, stream>>>(wo, wob, 262144);
  k_f2b<<<dim3(32000), dim3(256), 0, stream>>>(wfc, wfb, 8192000);

  // projections: q/k/v = x @ W^T
  k_gemm<1><<<dim3(32, 8), dim3(256), 0, stream>>>(xb, wqb, 4096, 1024, 1024, nullptr, qbf, nullptr);
  k_gemm<1><<<dim3(32, 8), dim3(256), 0, stream>>>(xb, wkb, 4096, 1024, 1024, nullptr, kbf, nullptr);
  k_gemm<1><<<dim3(32, 8), dim3(256), 0, stream>>>(xb, wvb, 4096, 1024, 1024, nullptr, vbf, nullptr);

  k_attn<<<dim3(32, 32), dim3(256), 0, stream>>>(qbf, kbf, vbf, cbf);

  // x2 = bf16(x + ctx @ wo^T)
  k_gemm<2><<<dim3(32, 8), dim3(256), 0, stream>>>(cbf, wob, 4096, 1024, 1024, nullptr, x2b, xf);

  // logits = x2 @ wfc^T  (fp32 out)
  k_gemm<0><<<dim3(32, 250), dim3(256), 0, stream>>>(x2b, wfb, 4096, 32000, 1024, out, nullptr, nullptr);
}

// Round 2
// 1141.911 us; speedup vs baseline: 1.0967x; 1.0967x over previous
//
#include <hip/hip_runtime.h>
#include <hip/hip_bf16.h>
#include <stdint.h>

#define VOCAB 32000
#define EMBED 1024
#define HEADS 16
#define SEQ   2048
#define BATCH 2
#define HD    64

typedef __attribute__((ext_vector_type(8))) __bf16 bf16x8;
typedef __attribute__((ext_vector_type(4))) __bf16 bf16x4;
typedef __attribute__((ext_vector_type(4))) float f32x4;
typedef __attribute__((ext_vector_type(8))) unsigned short u16x8;

__device__ __forceinline__ void gload16(const void* g, void* l) {
  __builtin_amdgcn_global_load_lds((const __attribute__((address_space(1))) void*)g,
                                   (__attribute__((address_space(3))) void*)l,
                                   16, 0, 0);
}
#define BAR() asm volatile("s_barrier" ::: "memory")

// ---------------- embed gather ----------------
__global__ __launch_bounds__(256) void k_embed(const int* __restrict__ idx,
                                               const float* __restrict__ emb,
                                               float* __restrict__ xf,
                                               __bf16* __restrict__ xb) {
  const int row = blockIdx.x;
  const int t = threadIdx.x;
  const int src = idx[row];
  float4 v = reinterpret_cast<const float4*>(emb + (size_t)src * EMBED)[t];
  reinterpret_cast<float4*>(xf + (size_t)row * EMBED)[t] = v;
  bf16x4 b;
  b[0] = (__bf16)v.x; b[1] = (__bf16)v.y; b[2] = (__bf16)v.z; b[3] = (__bf16)v.w;
  reinterpret_cast<bf16x4*>(xb + (size_t)row * EMBED)[t] = b;
}

// ---------------- f32 -> bf16 convert ----------------
__global__ __launch_bounds__(256) void k_f2b(const float* __restrict__ in,
                                             __bf16* __restrict__ out, int n4) {
  int i = blockIdx.x * 256 + threadIdx.x;
  if (i >= n4) return;
  float4 v = reinterpret_cast<const float4*>(in)[i];
  bf16x4 b;
  b[0] = (__bf16)v.x; b[1] = (__bf16)v.y; b[2] = (__bf16)v.z; b[3] = (__bf16)v.w;
  reinterpret_cast<bf16x4*>(out)[i] = b;
}

// ---------------- 128^2 m97-structure GEMM (projections / wo) ----------------
// MODE 1: bf16 C. MODE 2: bf16(C+resid).
template<int MODE>
__global__ __launch_bounds__(256) void k_gemm(const __bf16* __restrict__ A,
                                              const __bf16* __restrict__ Bt,
                                              int M, int N, int K,
                                              float* __restrict__ Cf,
                                              __bf16* __restrict__ Cb,
                                              const float* __restrict__ resid) {
  __shared__ __bf16 As[128 * 32];
  __shared__ __bf16 Bs[128 * 32];
  const int tid = threadIdx.x;
  const int wid = tid >> 6, lane = tid & 63;
  const int m0 = blockIdx.x * 128, n0 = blockIdx.y * 128;
  const int wr = wid >> 1, wc = wid & 1;

  const int arow = tid >> 2, acol = (tid & 3) * 8;
  const __bf16* ga0 = A + (size_t)(m0 + arow) * K + acol;
  const __bf16* ga1 = A + (size_t)(m0 + arow + 64) * K + acol;
  const __bf16* gb0 = Bt + (size_t)(n0 + arow) * K + acol;
  const __bf16* gb1 = Bt + (size_t)(n0 + arow + 64) * K + acol;
  __bf16* lA0 = As + wid * 512;
  __bf16* lA1 = As + wid * 512 + 2048;
  __bf16* lB0 = Bs + wid * 512;
  __bf16* lB1 = Bs + wid * 512 + 2048;

  f32x4 acc[4][4] = {};
  const int lr = lane & 15;
  const int kchunk = (lane >> 4) * 8;

  for (int k0 = 0; k0 < K; k0 += 32) {
    gload16(ga0 + k0, lA0);
    gload16(ga1 + k0, lA1);
    gload16(gb0 + k0, lB0);
    gload16(gb1 + k0, lB1);
    __syncthreads();
    bf16x8 a[4], b[4];
#pragma unroll
    for (int i = 0; i < 4; ++i) {
      a[i] = *reinterpret_cast<const bf16x8*>(&As[(wr * 64 + i * 16 + lr) * 32 + kchunk]);
      b[i] = *reinterpret_cast<const bf16x8*>(&Bs[(wc * 64 + i * 16 + lr) * 32 + kchunk]);
    }
#pragma unroll
    for (int i = 0; i < 4; ++i)
#pragma unroll
      for (int j = 0; j < 4; ++j)
        acc[i][j] = __builtin_amdgcn_mfma_f32_16x16x32_bf16(a[i], b[j], acc[i][j], 0, 0, 0);
    __syncthreads();
  }

  const int r0 = (lane >> 4) * 4;
#pragma unroll
  for (int i = 0; i < 4; ++i)
#pragma unroll
    for (int j = 0; j < 4; ++j)
#pragma unroll
      for (int r = 0; r < 4; ++r) {
        const int row = m0 + wr * 64 + i * 16 + r0 + r;
        const int col = n0 + wc * 64 + j * 16 + lr;
        const size_t o = (size_t)row * N + col;
        if constexpr (MODE == 1) Cb[o] = (__bf16)acc[i][j][r];
        else                     Cb[o] = (__bf16)(acc[i][j][r] + resid[o]);
      }
}

// ---------------- 256^2 / BK=64 pipelined GEMM (T1+T2+T3+T4+T5) ----------------
// 512 thr = 8 waves (2m x 4n), per-wave 128x64 out. LDS 2 bufs x 64KB.
// Buf layout (bytes from base): A-half0 [128r x 64k] @0, A-half1 @16384,
// B-half0 @32768, B-half1 @49152. Swizzle: phys_byte = byte ^ (((row>>2)&1)<<5),
// applied as pre-swizzled GLOBAL source (stage) + swizzled ds_read offset.
// Per K-tile: 4 phases (quadrants q0=(mlo,nlo) q1=(mlo,nhi) q2=(mhi,nhi) q3=(mhi,nlo)),
// each staging one quarter-unit (2 gload16/thread) of a future tile:
//   ph0:(t+1).Ahi ph1:(t+1).Bnlo ph2:(t+2).Alo ph3:(t+2).Bnhi
// (each write targets a region whose last LDS read is provably in an earlier phase).
// vmcnt(4) once per tile (tail: 0) => tile t+1 fully landed, 2 units stay in flight.
template<int MODE>
__global__ __launch_bounds__(512, 2) void k_gemm256(const __bf16* __restrict__ A,
                                                    const __bf16* __restrict__ Bt,
                                                    int M, int N, int K,
                                                    float* __restrict__ Cf,
                                                    __bf16* __restrict__ Cb,
                                                    const float* __restrict__ resid,
                                                    int grid_m) {
  __shared__ __bf16 lds[65536];   // 128 KB
  char* const sb = (char*)lds;

  const int tid = threadIdx.x;
  const int wid = tid >> 6, lane = tid & 63;
  const int wm = wid >> 2, wn = wid & 3;
  const int lr = lane & 15, lk = lane >> 4;

  // XCD-bijective block swizzle (m204), m-fast within chunk
  const int nwg = gridDim.x;
  const int orig = blockIdx.x;
  const int xcd = orig & 7, qq = nwg >> 3, rr = nwg & 7;
  const int wg = (xcd < rr ? xcd * (qq + 1) : rr * (qq + 1) + (xcd - rr) * qq) + (orig >> 3);
  const int m0 = (wg % grid_m) << 8;
  const int n0 = (wg / grid_m) << 8;
  const int nt = K >> 6;

  // ---- staging address precompute (per-thread) ----
  const int scc = (tid & 7) ^ (((tid >> 5) & 1) << 1);   // pre-swizzled col chunk
  const int sArow = tid >> 3;                            // 0..63 within A quarter
  const int sBrow = ((tid >> 8) & 1) * 64 + ((tid >> 3) & 31);
  const __bf16* aG[2][2];   // [s(half)][hi]
  const __bf16* bG[2][2];   // [s(half)][hiq]
#pragma unroll
  for (int s = 0; s < 2; ++s) {
#pragma unroll
    for (int h = 0; h < 2; ++h) {
      aG[s][h] = A + (size_t)(m0 + s * 128 + h * 64 + sArow) * K + scc * 8;
      bG[s][h] = Bt + (size_t)(n0 + s * 128 + sBrow + h * 32) * K + scc * 8;
    }
  }
  const int aDstW = wid * 1024;                              // within A quarter
  const int bDstW = (wm * 64 + wn * 8) * 128;                // within B half (+hiq*4096)

  auto stageA = [&](int t, int hi) {
    const int bb = (t & 1) << 16;
    const size_t ko = (size_t)(t << 6);
#pragma unroll
    for (int s = 0; s < 2; ++s)
      gload16(aG[s][hi] + ko, sb + bb + s * 16384 + hi * 8192 + aDstW);
  };
  auto stageB = [&](int t, int hiq) {
    const int bb = (t & 1) << 16;
    const size_t ko = (size_t)(t << 6);
#pragma unroll
    for (int s = 0; s < 2; ++s)
      gload16(bG[s][hiq] + ko, sb + bb + 32768 + s * 16384 + hiq * 4096 + bDstW);
  };

  // ---- fragment read precompute ----
  const int axor = ((lr >> 2) & 1) << 5;
  const int aBase = wm * 16384;
  const int bBase = 32768 + (wn >> 1) * 16384 + (wn & 1) * 8192;

  f32x4 acc[8][4] = {};
  bf16x8 Ar[4][2], Blo[2][2], Bhi[2][2];

  auto ldA = [&](int bb, int ih) {
    const char* p = sb + bb + aBase;
#pragma unroll
    for (int ii = 0; ii < 4; ++ii) {
      const int ro = (ih * 64 + ii * 16 + lr) * 128;
#pragma unroll
      for (int kk = 0; kk < 2; ++kk)
        Ar[ii][kk] = *reinterpret_cast<const bf16x8*>(p + ro + kk * 64 + ((lk * 16) ^ axor));
    }
  };
  auto ldB = [&](int bb, bf16x8 (&B)[2][2], int jh) {
    const char* p = sb + bb + bBase;
#pragma unroll
    for (int jj = 0; jj < 2; ++jj) {
      const int ro = ((jh * 2 + jj) * 16 + lr) * 128;
#pragma unroll
      for (int kk = 0; kk < 2; ++kk)
        B[jj][kk] = *reinterpret_cast<const bf16x8*>(p + ro + kk * 64 + ((lk * 16) ^ axor));
    }
  };
  auto mmaQ = [&](int i0, int j0, bf16x8 (&B)[2][2]) {
    __builtin_amdgcn_s_setprio(1);
#pragma unroll
    for (int ii = 0; ii < 4; ++ii)
#pragma unroll
      for (int jj = 0; jj < 2; ++jj)
#pragma unroll
        for (int kk = 0; kk < 2; ++kk)
          acc[i0 + ii][j0 + jj] = __builtin_amdgcn_mfma_f32_16x16x32_bf16(
              Ar[ii][kk], B[jj][kk], acc[i0 + ii][j0 + jj], 0, 0, 0);
    __builtin_amdgcn_s_setprio(0);
  };

  // ---- prologue: tile0 complete + tile1 {Alo, Bnhi} ----
  stageA(0, 0); stageB(0, 1); stageA(0, 1); stageB(0, 0);
  stageA(1, 0); stageB(1, 1);
  asm volatile("s_waitcnt vmcnt(4)" ::: "memory");
  __builtin_amdgcn_sched_barrier(0);
  BAR();

  // ---- main loop ----
  for (int t = 0; t < nt; ++t) {
    const int bb = (t & 1) << 16;
    // phase 0: (mlo, nlo)
    ldA(bb, 0); ldB(bb, Blo, 0);
    if (t + 1 < nt) stageA(t + 1, 1);
    BAR();
    mmaQ(0, 0, Blo);
    BAR();
    // phase 1: (mlo, nhi)
    ldB(bb, Bhi, 1);
    if (t + 1 < nt) stageB(t + 1, 0);
    BAR();
    mmaQ(0, 2, Bhi);
    BAR();
    // phase 2: (mhi, nhi)
    ldA(bb, 1);
    if (t + 2 < nt) stageA(t + 2, 0);
    BAR();
    mmaQ(4, 2, Bhi);
    BAR();
    // phase 3: (mhi, nlo)  — Blo regs reused from phase 0
    if (t + 2 < nt) stageB(t + 2, 1);
    if (t < nt - 1) {
      if (t + 2 < nt) { asm volatile("s_waitcnt vmcnt(4)" ::: "memory"); }
      else            { asm volatile("s_waitcnt vmcnt(0)" ::: "memory"); }
      __builtin_amdgcn_sched_barrier(0);
    }
    BAR();
    mmaQ(4, 0, Blo);
    BAR();
  }

  // ---- epilogue ----
  const int rbase = m0 + wm * 128 + lk * 4;
  const int cbase = n0 + wn * 64 + lr;
#pragma unroll
  for (int i = 0; i < 8; ++i)
#pragma unroll
    for (int j = 0; j < 4; ++j)
#pragma unroll
      for (int r = 0; r < 4; ++r) {
        const size_t o = (size_t)(rbase + i * 16 + r) * N + (cbase + j * 16);
        if constexpr (MODE == 0)      Cf[o] = acc[i][j][r];
        else if constexpr (MODE == 1) Cb[o] = (__bf16)acc[i][j][r];
        else                          Cb[o] = (__bf16)(acc[i][j][r] + resid[o]);
      }
}

// ---------------- causal flash attention (ld-strided q/k/v) ----------------
__global__ __launch_bounds__(256) void k_attn(const __bf16* __restrict__ qb,
                                              const __bf16* __restrict__ kb,
                                              const __bf16* __restrict__ vb,
                                              __bf16* __restrict__ ctx, int ld) {
  __shared__ __bf16 Ks[64 * 64];
  __shared__ __bf16 Vt[64 * 64];
  __shared__ __bf16 Ps[4][16 * 64];

  const int tid = threadIdx.x, wid = tid >> 6, lane = tid & 63;
  const int bq = blockIdx.x;
  const int bh = blockIdx.y;
  const int b = bh >> 4, h = bh & 15;
  const int q0 = bq * 64;

  const size_t qoff = (size_t)(b * SEQ + q0 + wid * 16 + (lane & 15)) * ld + h * HD;
  const bf16x8 qf0 = *reinterpret_cast<const bf16x8*>(qb + qoff + (lane >> 4) * 8);
  const bf16x8 qf1 = *reinterpret_cast<const bf16x8*>(qb + qoff + 32 + (lane >> 4) * 8);

  const int krow = tid >> 3;
  const int kcs = (tid & 7) ^ (krow & 7);
  const __bf16* kg = kb + (size_t)(b * SEQ + krow) * ld + h * HD + kcs * 8;
  __bf16* lK0 = Ks + wid * 512;
  __bf16* lK1 = Ks + wid * 512 + 2048;

  const int vkv = (tid & 31) * 2;
  const int vd0 = (tid >> 5) * 8;
  const __bf16* vg = vb + (size_t)(b * SEQ + vkv) * ld + h * HD + vd0;

  f32x4 o[4] = {};
  float mrow[4] = {-1e30f, -1e30f, -1e30f, -1e30f};
  float lsum[4] = {0.f, 0.f, 0.f, 0.f};

  char* const pbase = (char*)&Ps[wid][0];
  const char* const ksb = (const char*)Ks;
  const char* const vtb = (const char*)Vt;

  const int ntiles = bq + 1;
  for (int t = 0; t < ntiles; ++t) {
    const size_t kvo = (size_t)t * 64 * ld;
    gload16(kg + kvo, lK0);
    gload16(kg + kvo + (size_t)32 * ld, lK1);
    u16x8 v0 = *reinterpret_cast<const u16x8*>(vg + kvo);
    u16x8 v1 = *reinterpret_cast<const u16x8*>(vg + kvo + ld);
#pragma unroll
    for (int j = 0; j < 8; ++j) {
      uint32_t val = (uint32_t)v0[j] | ((uint32_t)v1[j] << 16);
      *(uint32_t*)((char*)Vt + (vd0 + j) * 128 + ((vkv * 2) ^ (j << 4))) = val;
    }
    __syncthreads();

    f32x4 s[4];
#pragma unroll
    for (int nb = 0; nb < 4; ++nb) {
      const int n = nb * 16 + (lane & 15);
      const int c0 = (lane >> 4) ^ (n & 7);
      const int c1 = ((lane >> 4) + 4) ^ (n & 7);
      bf16x8 kf0 = *reinterpret_cast<const bf16x8*>(ksb + n * 128 + c0 * 16);
      bf16x8 kf1 = *reinterpret_cast<const bf16x8*>(ksb + n * 128 + c1 * 16);
      f32x4 z = {};
      z = __builtin_amdgcn_mfma_f32_16x16x32_bf16(qf0, kf0, z, 0, 0, 0);
      z = __builtin_amdgcn_mfma_f32_16x16x32_bf16(qf1, kf1, z, 0, 0, 0);
      s[nb] = z;
    }

    const int kvb = t * 64;
    const int qrow0 = q0 + wid * 16 + (lane >> 4) * 4;
#pragma unroll
    for (int nb = 0; nb < 4; ++nb) {
      const int kcol = kvb + nb * 16 + (lane & 15);
#pragma unroll
      for (int r = 0; r < 4; ++r) {
        float x = s[nb][r] * 0.125f;
        s[nb][r] = (kcol <= qrow0 + r) ? x : -1e30f;
      }
    }

    float pmax[4], alpha[4], rsum[4];
#pragma unroll
    for (int r = 0; r < 4; ++r)
      pmax[r] = fmaxf(fmaxf(s[0][r], s[1][r]), fmaxf(s[2][r], s[3][r]));
#pragma unroll
    for (int off = 1; off < 16; off <<= 1)
#pragma unroll
      for (int r = 0; r < 4; ++r)
        pmax[r] = fmaxf(pmax[r], __shfl_xor(pmax[r], off, 64));
#pragma unroll
    for (int r = 0; r < 4; ++r) {
      float mn = fmaxf(mrow[r], pmax[r]);
      alpha[r] = __expf(mrow[r] - mn);
      mrow[r] = mn;
      rsum[r] = 0.f;
    }
#pragma unroll
    for (int nb = 0; nb < 4; ++nb)
#pragma unroll
      for (int r = 0; r < 4; ++r) {
        float p = __expf(s[nb][r] - mrow[r]);
        s[nb][r] = p;
        rsum[r] += p;
      }
#pragma unroll
    for (int off = 1; off < 16; off <<= 1)
#pragma unroll
      for (int r = 0; r < 4; ++r)
        rsum[r] += __shfl_xor(rsum[r], off, 64);
#pragma unroll
    for (int r = 0; r < 4; ++r)
      lsum[r] = lsum[r] * alpha[r] + rsum[r];
#pragma unroll
    for (int nb = 0; nb < 4; ++nb)
#pragma unroll
      for (int r = 0; r < 4; ++r)
        o[nb][r] *= alpha[r];

#pragma unroll
    for (int nb = 0; nb < 4; ++nb)
#pragma unroll
      for (int r = 0; r < 4; ++r) {
        const int pr = (lane >> 4) * 4 + r;
        const int pc = nb * 16 + (lane & 15);
        *(__bf16*)(pbase + pr * 128 + ((pc * 2) ^ ((pr & 7) << 4))) = (__bf16)s[nb][r];
      }
    const int ar = lane & 15;
    const int aswz = (ar & 7) << 4;
    bf16x8 pf0 = *reinterpret_cast<const bf16x8*>(pbase + ar * 128 + (((lane >> 4) * 16) ^ aswz));
    bf16x8 pf1 = *reinterpret_cast<const bf16x8*>(pbase + ar * 128 + ((64 + (lane >> 4) * 16) ^ aswz));

#pragma unroll
    for (int nb = 0; nb < 4; ++nb) {
      const int n = nb * 16 + (lane & 15);
      const int vswz = (n & 7) << 4;
      bf16x8 vf0 = *reinterpret_cast<const bf16x8*>(vtb + n * 128 + (((lane >> 4) * 16) ^ vswz));
      bf16x8 vf1 = *reinterpret_cast<const bf16x8*>(vtb + n * 128 + ((64 + (lane >> 4) * 16) ^ vswz));
      o[nb] = __builtin_amdgcn_mfma_f32_16x16x32_bf16(pf0, vf0, o[nb], 0, 0, 0);
      o[nb] = __builtin_amdgcn_mfma_f32_16x16x32_bf16(pf1, vf1, o[nb], 0, 0, 0);
    }
    __syncthreads();
  }

  const int orow = q0 + wid * 16 + (lane >> 4) * 4;
#pragma unroll
  for (int nb = 0; nb < 4; ++nb)
#pragma unroll
    for (int r = 0; r < 4; ++r) {
      const float v = o[nb][r] / lsum[r];
      ctx[(size_t)(b * SEQ + orow + r) * EMBED + h * HD + nb * 16 + (lane & 15)] = (__bf16)v;
    }
}

// ---------------- launch ----------------
extern "C" void kernel_launch(void* const* d_in, const int* in_sizes, int n_in,
                              void* d_out, int out_size, void* d_ws, size_t ws_size,
                              hipStream_t stream) {
  const int*   idx = (const int*)d_in[0];
  const float* emb = (const float*)d_in[1];
  const float* wq  = (const float*)d_in[2];
  const float* wk  = (const float*)d_in[3];
  const float* wv  = (const float*)d_in[4];
  const float* wo  = (const float*)d_in[5];
  const float* wfc = (const float*)d_in[6];
  float* out = (float*)d_out;

  char* ws = (char*)d_ws;
  float*  xf  = (float*)(ws);                  // 16 MB fp32 x (residual)
  __bf16* xb  = (__bf16*)(ws + 16777216);      // 8 MB
  __bf16* qkv = (__bf16*)(ws + 25165824);      // 24 MB [4096][3072]
  __bf16* cbf = (__bf16*)(ws + 50331648);      // 8 MB attention ctx
  __bf16* x2b = (__bf16*)(ws + 58720256);      // 8 MB
  __bf16* wqb = (__bf16*)(ws + 67108864);      // 2+2+2 MB (contiguous qkv weights)
  __bf16* wob = (__bf16*)(ws + 73400320);      // 2 MB
  __bf16* wfb = (__bf16*)(ws + 75497472);      // 65.5 MB

  k_embed<<<dim3(4096), dim3(256), 0, stream>>>(idx, emb, xf, xb);
  k_f2b<<<dim3(1024), dim3(256), 0, stream>>>(wq, wqb, 262144);
  k_f2b<<<dim3(1024), dim3(256), 0, stream>>>(wk, wqb + 1048576, 262144);
  k_f2b<<<dim3(1024), dim3(256), 0, stream>>>(wv, wqb + 2097152, 262144);
  k_f2b<<<dim3(1024), dim3(256), 0, stream>>>(wo, wob, 262144);
  k_f2b<<<dim3(32000), dim3(256), 0, stream>>>(wfc, wfb, 8192000);

  // fused qkv projection: [4096,3072] = x @ [wq;wk;wv]^T
  k_gemm<1><<<dim3(32, 24), dim3(256), 0, stream>>>(xb, wqb, 4096, 3072, 1024, nullptr, qkv, nullptr);

  k_attn<<<dim3(32, 32), dim3(256), 0, stream>>>(qkv, qkv + 1024, qkv + 2048, cbf, 3072);

  // x2 = bf16(x + ctx @ wo^T)
  k_gemm<2><<<dim3(32, 8), dim3(256), 0, stream>>>(cbf, wob, 4096, 1024, 1024, nullptr, x2b, xf);

  // logits = x2 @ wfc^T (fp32 out) — 256^2 pipelined kernel, 2000 blocks
  k_gemm256<0><<<dim3(2000), dim3(512), 0, stream>>>(x2b, wfb, 4096, 32000, 1024, out, nullptr, nullptr, 16);
}